// Round 3
// baseline (208.340 us; speedup 1.0000x reference)
//
#include <hip/hip_runtime.h>
#include <math.h>

#define B_DIM 256
#define M_DIM 4096
#define EPSV 1e-7f
#define QPR   4                    // quarters per row
#define QSIZE (M_DIM / QPR)        // 1024 elements per quarter
#define K1_THREADS 256
#define K1_ELEMS   (QSIZE / K1_THREADS)  // 4 elements per thread

// ws layout:
//   doubles [0..5]: coord_num, width_num, validity_sum, n_valid, cont_sum, recon_sum
//   floats at byte offset 64: per-quarter records, 1024 quarters x 6 floats
//     {has, first_p4, first_p5, last_p4, last_p5, pad}

__global__ __launch_bounds__(K1_THREADS, 4) void row_loss_kernel(
    const float* __restrict__ pred, const float* __restrict__ tgt,
    double* __restrict__ ws, float* __restrict__ rec_ws)
{
    __shared__ float s_p4[QSIZE];                 // 4 KB
    __shared__ float s_p5[QSIZE];                 // 4 KB
    __shared__ unsigned long long s_words[QSIZE / 64]; // 16 words
    __shared__ float s_red[4][5];

    const int q    = blockIdx.x;        // quarter id 0..1023
    const int row  = q >> 2;
    const int qi   = q & 3;
    const int t    = threadIdx.x;
    const int lane = t & 63;
    const int wave = t >> 6;            // 0..3

    const float* prow = pred + ((size_t)row * M_DIM + qi * QSIZE) * 9;
    const float* trow = tgt  + ((size_t)row * M_DIM + qi * QSIZE) * 9;

    float coord_s = 0.f, width_s = 0.f, val_s = 0.f, nval_s = 0.f;
    bool valid_k[K1_ELEMS];

    #pragma unroll
    for (int k = 0; k < K1_ELEMS; ++k) {
        const int m = k * K1_THREADS + t;       // local element 0..1023
        const float* p = prow + m * 9;
        const float* qq = trow + m * 9;
        float p0 = p[0], p1 = p[1], p2 = p[2], p3 = p[3], p4 = p[4],
              p5 = p[5], p6 = p[6], p7 = p[7], p8 = p[8];
        float t0 = qq[0], t1 = qq[1], t2 = qq[2], t3 = qq[3], t4 = qq[4],
              t5 = qq[5], t6 = qq[6], t7 = qq[7], t8 = qq[8];

        bool valid = (t8 > 0.5f);
        valid_k[k] = valid;
        float fm = valid ? 1.f : 0.f;
        coord_s += fm * (fabsf(p0 - t0) + fabsf(p1 - t1) + fabsf(p2 - t2) +
                         fabsf(p3 - t3) + fabsf(p4 - t4) + fabsf(p5 - t5));
        width_s += fm * (fabsf(p6 - t6) + fabsf(p7 - t7));
        nval_s  += fm;

        float pc = fminf(fmaxf(p8, EPSV), 1.0f - EPSV);
        val_s += -(t8 * __logf(pc) + (1.0f - t8) * __logf(1.0f - pc));

        s_p4[m] = p4;
        s_p5[m] = p5;
        unsigned long long bal = __ballot(valid);
        if (lane == 0) s_words[k * 4 + wave] = bal;
    }
    __syncthreads();

    // Quarter-local continuity: next-valid bit-scan within 1024 elements.
    float cont_s = 0.f;
    #pragma unroll
    for (int k = 0; k < K1_ELEMS; ++k) {
        if (!valid_k[k]) continue;
        const int m   = k * K1_THREADS + t;
        const int w   = m >> 6;
        const int bit = m & 63;
        unsigned long long mask = s_words[w];
        mask &= (bit == 63) ? 0ULL : (~0ULL << (bit + 1));
        int nxt = -1;
        if (mask) {
            nxt = (w << 6) + __builtin_ctzll(mask);
        } else {
            for (int w2 = w + 1; w2 < (QSIZE / 64); ++w2) {
                unsigned long long mw = s_words[w2];
                if (mw) { nxt = (w2 << 6) + __builtin_ctzll(mw); break; }
            }
        }
        if (nxt >= 0) {
            cont_s += 0.5f * (fabsf(s_p4[m] - s_p4[nxt]) +
                              fabsf(s_p5[m] - s_p5[nxt]));
        }
    }

    // Block reduction of 5 partials (4 waves).
    float vals[5] = {coord_s, width_s, val_s, nval_s, cont_s};
    #pragma unroll
    for (int i = 0; i < 5; ++i) {
        float v = vals[i];
        #pragma unroll
        for (int off = 32; off > 0; off >>= 1) v += __shfl_down(v, off, 64);
        vals[i] = v;
    }
    if (lane == 0) {
        #pragma unroll
        for (int i = 0; i < 5; ++i) s_red[wave][i] = vals[i];
    }
    __syncthreads();
    if (t == 0) {
        float acc[5] = {0.f, 0.f, 0.f, 0.f, 0.f};
        for (int wv = 0; wv < 4; ++wv)
            #pragma unroll
            for (int i = 0; i < 5; ++i) acc[i] += s_red[wv][i];
        atomicAdd(&ws[0], (double)acc[0]);
        atomicAdd(&ws[1], (double)acc[1]);
        atomicAdd(&ws[2], (double)acc[2]);
        atomicAdd(&ws[3], (double)acc[3]);
        atomicAdd(&ws[4], (double)acc[4]);

        // Per-quarter boundary record: first/last valid element's (p4,p5).
        int first = -1, last = -1;
        for (int w = 0; w < (QSIZE / 64); ++w) {
            unsigned long long mw = s_words[w];
            if (mw) { first = (w << 6) + __builtin_ctzll(mw); break; }
        }
        for (int w = (QSIZE / 64) - 1; w >= 0; --w) {
            unsigned long long mw = s_words[w];
            if (mw) { last = (w << 6) + 63 - __builtin_clzll(mw); break; }
        }
        float* r = rec_ws + q * 6;
        if (first >= 0) {
            r[0] = 1.f;
            r[1] = s_p4[first]; r[2] = s_p5[first];
            r[3] = s_p4[last];  r[4] = s_p5[last];
        } else {
            r[0] = 0.f; r[1] = 0.f; r[2] = 0.f; r[3] = 0.f; r[4] = 0.f;
        }
        r[5] = 0.f;
    }
}

__global__ __launch_bounds__(256) void recon_kernel(
    const float4* __restrict__ rec, const float4* __restrict__ img,
    double* __restrict__ ws)
{
    const int n4     = (B_DIM * 128 * 128) / 4;   // 1048576
    const int stride = gridDim.x * blockDim.x;    // 2048*256 = 524288
    int idx = blockIdx.x * blockDim.x + threadIdx.x;
    float s = 0.f;
    for (int i = idx; i < n4; i += stride) {      // 2 iters
        float4 r = rec[i]; float4 m = img[i];
        float d0 = r.x - m.x, d1 = r.y - m.y, d2 = r.z - m.z, d3 = r.w - m.w;
        s += d0 * d0 + d1 * d1 + d2 * d2 + d3 * d3;
    }
    #pragma unroll
    for (int off = 32; off > 0; off >>= 1) s += __shfl_down(s, off, 64);
    __shared__ float sred[4];
    int lane = threadIdx.x & 63, wave = threadIdx.x >> 6;
    if (lane == 0) sred[wave] = s;
    __syncthreads();
    if (threadIdx.x == 0) {
        atomicAdd(&ws[5], (double)(sred[0] + sred[1] + sred[2] + sred[3]));
    }
}

__global__ __launch_bounds__(256) void finalize_kernel(
    const double* __restrict__ ws, const float* __restrict__ rec_ws,
    float* __restrict__ out)
{
    const int t = threadIdx.x;          // one row per thread
    // Cross-quarter boundary continuity pairs.
    float cont_extra = 0.f;
    {
        const float* base = rec_ws + t * QPR * 6;
        bool  have = false;
        float pl4 = 0.f, pl5 = 0.f;
        #pragma unroll
        for (int q = 0; q < QPR; ++q) {
            const float* r = base + q * 6;
            if (r[0] > 0.5f) {
                if (have)
                    cont_extra += 0.5f * (fabsf(pl4 - r[1]) + fabsf(pl5 - r[2]));
                pl4 = r[3]; pl5 = r[4];
                have = true;
            }
        }
    }
    #pragma unroll
    for (int off = 32; off > 0; off >>= 1)
        cont_extra += __shfl_down(cont_extra, off, 64);
    __shared__ float sred[4];
    int lane = t & 63, wave = t >> 6;
    if (lane == 0) sred[wave] = cont_extra;
    __syncthreads();
    if (t == 0) {
        double cont = ws[4] + (double)(sred[0] + sred[1] + sred[2] + sred[3]);
        double coord_num = ws[0];
        double width_num = ws[1];
        double val_sum   = ws[2];
        double nv        = ws[3];
        double recon     = ws[5];

        double coord = (nv > 0.0) ? coord_num / fmax(nv * 6.0, 1.0) : 0.0;
        double width = (nv > 0.0) ? width_num / fmax(nv * 2.0, 1.0) : 0.0;
        double validity = val_sum / ((double)B_DIM * (double)M_DIM);
        double contl    = cont / (double)B_DIM;
        double reconl   = recon / ((double)B_DIM * 128.0 * 128.0);

        out[0] = (float)(coord + width + 2.0 * validity +
                         0.2 * contl + 0.1 * reconl);
    }
}

extern "C" void kernel_launch(void* const* d_in, const int* in_sizes, int n_in,
                              void* d_out, int out_size, void* d_ws, size_t ws_size,
                              hipStream_t stream) {
    const float* pred = (const float*)d_in[0];
    const float* tgt  = (const float*)d_in[1];
    const float* rec  = (const float*)d_in[2];
    const float* img  = (const float*)d_in[3];
    double* ws = (double*)d_ws;
    float* rec_ws = (float*)((char*)d_ws + 64);

    hipMemsetAsync(d_ws, 0, 6 * sizeof(double), stream);

    row_loss_kernel<<<B_DIM * QPR, K1_THREADS, 0, stream>>>(pred, tgt, ws, rec_ws);
    recon_kernel<<<2048, 256, 0, stream>>>((const float4*)rec, (const float4*)img, ws);
    finalize_kernel<<<1, 256, 0, stream>>>(ws, rec_ws, (float*)d_out);
}

// Round 4
// 169.755 us; speedup vs baseline: 1.2273x; 1.2273x over previous
//
#include <hip/hip_runtime.h>
#include <math.h>

#define B_DIM 256
#define M_DIM 4096
#define EPSV 1e-7f
#define THREADS 1024

// ws layout (doubles):
// 0: coord_num, 1: width_num, 2: validity_sum, 3: n_valid, 4: cont_sum, 5: recon_sum

// spread 16 bits so bit i -> bit 4i
__device__ __forceinline__ unsigned long long spread4(unsigned long long x) {
    x &= 0xFFFFULL;
    x = (x | (x << 24)) & 0x000000FF000000FFULL;
    x = (x | (x << 12)) & 0x000F000F000F000FULL;
    x = (x | (x << 6))  & 0x0303030303030303ULL;
    x = (x | (x << 3))  & 0x1111111111111111ULL;
    return x;
}

// constant-index float4-array component access (folds after unroll)
#define VF(arr, i) (((i) & 3) == 0 ? arr[(i) >> 2].x : \
                    ((i) & 3) == 1 ? arr[(i) >> 2].y : \
                    ((i) & 3) == 2 ? arr[(i) >> 2].z : arr[(i) >> 2].w)

__global__ __launch_bounds__(THREADS, 4) void row_loss_kernel(
    const float* __restrict__ pred, const float* __restrict__ tgt,
    double* __restrict__ ws)
{
    __shared__ float s_p4[M_DIM];                      // 16 KB
    __shared__ float s_p5[M_DIM];                      // 16 KB
    __shared__ unsigned long long s_words[M_DIM / 64]; // 512 B
    __shared__ float s_red[16][5];

    const int b    = blockIdx.x;
    const int t    = threadIdx.x;
    const int lane = t & 63;
    const int wave = t >> 6;   // 0..15

    const float4* pf4 = (const float4*)(pred + (size_t)b * M_DIM * 9);
    const float4* tf4 = (const float4*)(tgt  + (size_t)b * M_DIM * 9);

    // ---- vectorized load: thread t owns elements 4t..4t+3 = float4 [9t, 9t+9) ----
    float4 pr[9], tr[9];
    #pragma unroll
    for (int j = 0; j < 9; ++j) pr[j] = pf4[9 * t + j];
    #pragma unroll
    for (int j = 0; j < 9; ++j) tr[j] = tf4[9 * t + j];

    float coord_s = 0.f, width_s = 0.f, val_s = 0.f, nval_s = 0.f;
    float vp4[4], vp5[4];
    bool vld[4];

    #pragma unroll
    for (int e = 0; e < 4; ++e) {
        float p0 = VF(pr, e * 9 + 0), p1 = VF(pr, e * 9 + 1), p2 = VF(pr, e * 9 + 2);
        float p3 = VF(pr, e * 9 + 3), p4 = VF(pr, e * 9 + 4), p5 = VF(pr, e * 9 + 5);
        float p6 = VF(pr, e * 9 + 6), p7 = VF(pr, e * 9 + 7), p8 = VF(pr, e * 9 + 8);
        float t0 = VF(tr, e * 9 + 0), t1 = VF(tr, e * 9 + 1), t2 = VF(tr, e * 9 + 2);
        float t3 = VF(tr, e * 9 + 3), t4 = VF(tr, e * 9 + 4), t5 = VF(tr, e * 9 + 5);
        float t6 = VF(tr, e * 9 + 6), t7 = VF(tr, e * 9 + 7), t8 = VF(tr, e * 9 + 8);

        bool valid = (t8 > 0.5f);
        vld[e] = valid;
        float fm = valid ? 1.f : 0.f;
        coord_s += fm * (fabsf(p0 - t0) + fabsf(p1 - t1) + fabsf(p2 - t2) +
                         fabsf(p3 - t3) + fabsf(p4 - t4) + fabsf(p5 - t5));
        width_s += fm * (fabsf(p6 - t6) + fabsf(p7 - t7));
        nval_s  += fm;

        float pc = fminf(fmaxf(p8, EPSV), 1.0f - EPSV);
        val_s += -(t8 * __logf(pc) + (1.0f - t8) * __logf(1.0f - pc));

        vp4[e] = p4;
        vp5[e] = p5;
    }

    ((float4*)s_p4)[t] = make_float4(vp4[0], vp4[1], vp4[2], vp4[3]);
    ((float4*)s_p5)[t] = make_float4(vp5[0], vp5[1], vp5[2], vp5[3]);

    // ---- validity bitmask: 4 ballots + bit-interleave; lanes 0-3 write 4 words ----
    unsigned long long bal[4];
    #pragma unroll
    for (int e = 0; e < 4; ++e) bal[e] = __ballot(vld[e]);
    if (lane < 4) {
        // word (wave*4 + lane) covers wave-local elements 64*lane..64*lane+63
        // = lanes 16*lane..16*lane+15, bit 4i+j = vld[j] of lane 16*lane+i
        unsigned long long w = 0;
        #pragma unroll
        for (int j = 0; j < 4; ++j)
            w |= spread4(bal[j] >> (16 * lane)) << j;
        s_words[wave * 4 + lane] = w;
    }
    __syncthreads();

    // ---- continuity: next-valid bit-scan over full row ----
    float cont_s = 0.f;
    #pragma unroll
    for (int e = 0; e < 4; ++e) {
        if (!vld[e]) continue;
        const int m   = 4 * t + e;
        const int w   = m >> 6;
        const int bit = m & 63;
        unsigned long long mask = s_words[w];
        mask &= (bit == 63) ? 0ULL : (~0ULL << (bit + 1));
        int nxt = -1;
        if (mask) {
            nxt = (w << 6) + __builtin_ctzll(mask);
        } else {
            for (int w2 = w + 1; w2 < (M_DIM / 64); ++w2) {
                unsigned long long mw = s_words[w2];
                if (mw) { nxt = (w2 << 6) + __builtin_ctzll(mw); break; }
            }
        }
        if (nxt >= 0) {
            cont_s += 0.5f * (fabsf(s_p4[m] - s_p4[nxt]) +
                              fabsf(s_p5[m] - s_p5[nxt]));
        }
    }

    // ---- block reduction of 5 partials ----
    float vals[5] = {coord_s, width_s, val_s, nval_s, cont_s};
    #pragma unroll
    for (int i = 0; i < 5; ++i) {
        float v = vals[i];
        #pragma unroll
        for (int off = 32; off > 0; off >>= 1) v += __shfl_down(v, off, 64);
        vals[i] = v;
    }
    if (lane == 0) {
        #pragma unroll
        for (int i = 0; i < 5; ++i) s_red[wave][i] = vals[i];
    }
    __syncthreads();
    if (t == 0) {
        float acc[5] = {0.f, 0.f, 0.f, 0.f, 0.f};
        for (int wv = 0; wv < 16; ++wv)
            #pragma unroll
            for (int i = 0; i < 5; ++i) acc[i] += s_red[wv][i];
        atomicAdd(&ws[0], (double)acc[0]);
        atomicAdd(&ws[1], (double)acc[1]);
        atomicAdd(&ws[2], (double)acc[2]);
        atomicAdd(&ws[3], (double)acc[3]);
        atomicAdd(&ws[4], (double)acc[4]);
    }
}

__global__ __launch_bounds__(256) void recon_kernel(
    const float4* __restrict__ rec, const float4* __restrict__ img,
    double* __restrict__ ws)
{
    const int n4     = (B_DIM * 128 * 128) / 4;   // 1048576
    const int stride = gridDim.x * blockDim.x;    // 524288
    int idx = blockIdx.x * blockDim.x + threadIdx.x;
    float s = 0.f;
    for (int i = idx; i < n4; i += stride) {      // 2 iters
        float4 r = rec[i]; float4 m = img[i];
        float d0 = r.x - m.x, d1 = r.y - m.y, d2 = r.z - m.z, d3 = r.w - m.w;
        s += d0 * d0 + d1 * d1 + d2 * d2 + d3 * d3;
    }
    #pragma unroll
    for (int off = 32; off > 0; off >>= 1) s += __shfl_down(s, off, 64);
    __shared__ float sred[4];
    int lane = threadIdx.x & 63, wave = threadIdx.x >> 6;
    if (lane == 0) sred[wave] = s;
    __syncthreads();
    if (threadIdx.x == 0) {
        atomicAdd(&ws[5], (double)(sred[0] + sred[1] + sred[2] + sred[3]));
    }
}

__global__ void finalize_kernel(const double* __restrict__ ws,
                                float* __restrict__ out)
{
    double coord_num = ws[0];
    double width_num = ws[1];
    double val_sum   = ws[2];
    double nv        = ws[3];
    double cont      = ws[4];
    double recon     = ws[5];

    double coord = (nv > 0.0) ? coord_num / fmax(nv * 6.0, 1.0) : 0.0;
    double width = (nv > 0.0) ? width_num / fmax(nv * 2.0, 1.0) : 0.0;
    double validity = val_sum / ((double)B_DIM * (double)M_DIM);
    double contl    = cont / (double)B_DIM;
    double reconl   = recon / ((double)B_DIM * 128.0 * 128.0);

    out[0] = (float)(coord + width + 2.0 * validity +
                     0.2 * contl + 0.1 * reconl);
}

extern "C" void kernel_launch(void* const* d_in, const int* in_sizes, int n_in,
                              void* d_out, int out_size, void* d_ws, size_t ws_size,
                              hipStream_t stream) {
    const float* pred = (const float*)d_in[0];
    const float* tgt  = (const float*)d_in[1];
    const float* rec  = (const float*)d_in[2];
    const float* img  = (const float*)d_in[3];
    double* ws = (double*)d_ws;

    hipMemsetAsync(d_ws, 0, 6 * sizeof(double), stream);

    row_loss_kernel<<<B_DIM, THREADS, 0, stream>>>(pred, tgt, ws);
    recon_kernel<<<2048, 256, 0, stream>>>((const float4*)rec, (const float4*)img, ws);
    finalize_kernel<<<1, 1, 0, stream>>>(ws, (float*)d_out);
}